// Round 9
// baseline (290.870 us; speedup 1.0000x reference)
//
#include <hip/hip_runtime.h>

#define OBS 128
#define ACTD 32
#define DIMX 160
#define HID 64
#define NBATCH 32768
#define TMAXX 8
#define CTR 7
#define NPOS 15

typedef short bf16x8 __attribute__((ext_vector_type(8)));
typedef float f32x4 __attribute__((ext_vector_type(4)));

#define MFMA(a,b,c) __builtin_amdgcn_mfma_f32_16x16x32_bf16((a),(b),(c),0,0,0)

// ws layout (bytes):
//   [0)       lens: len_f[32768], len_b[32768] ints
//   [262144)  ctrl ints: [0..16] region starts (LPT order); [17..32] region->bin;
//             [40+) blockBase[64][16]; [40+1024+) blockHist[64][16]
//   [278528)  sidx[66048] ints (bins padded to x32, -1 sentinel)
//   [542720)  bf16 weights, fragment-major
//   [755712)  comb bf16 [elem][64*d + hunit] (8.4 MB)
#define CTRL_BYTE 262144
#define SIDX_BYTE 278528
#define SIDX_CAP  66048
#define WB_BYTE   542720
#define COMB_BYTE 755712
#define NCB 64
#define EPB 512
#define BB_OFF 40
#define BH_OFF (40 + 1024)
#define HEAD_W_OFF 10752
#define TOTAL_SLOTS 13312

__device__ __forceinline__ unsigned short f2bf(float f) {
  unsigned u = __float_as_uint(f);
  return (unsigned short)((u + 0x7FFFu + ((u >> 16) & 1u)) >> 16);
}
__device__ __forceinline__ unsigned cvtpk(float a, float b) {
  unsigned r;
  asm("v_cvt_pk_bf16_f32 %0, %1, %2" : "=v"(r) : "v"(a), "v"(b));
  return r;
}
// volatile 16B global read: defeats LICM so the fragment is NOT register-resident
__device__ __forceinline__ bf16x8 vload16(const unsigned short* p) {
  union { unsigned u[4]; bf16x8 h; } c;
  const volatile unsigned* vp = (const volatile unsigned*)p;
  c.u[0] = vp[0]; c.u[1] = vp[1]; c.u[2] = vp[2]; c.u[3] = vp[3];
  return c.h;
}

__device__ __forceinline__ float wsum(float v) {
#pragma unroll
  for (int s = 1; s < 64; s <<= 1) v += __shfl_xor(v, s);
  return v;
}
__device__ __forceinline__ float wmax(float v) {
#pragma unroll
  for (int s = 1; s < 64; s <<= 1) v = fmaxf(v, __shfl_xor(v, s));
  return v;
}

// ---------------- prep: weights -> bf16, fragment-major ----------------
__global__ __launch_bounds__(256) void k_prep(
    const float* __restrict__ Wih_f, const float* __restrict__ Whh_f,
    const float* __restrict__ Wih_b, const float* __restrict__ Whh_b,
    const float* __restrict__ mw1, const float* __restrict__ mw2,
    const float* __restrict__ mu_w, const float* __restrict__ lv_w,
    unsigned short* __restrict__ dst) {
  int slot = blockIdx.x * 256 + threadIdx.x;
  if (slot >= TOTAL_SLOTS) return;
  const float* src;
  if (slot < HEAD_W_OFF) {
    int d = slot / 5376, r = slot % 5376;
    int f = r >> 8, rw = r & 255;
    int w = rw >> 6, lane = rw & 63;
    int col = lane & 15, kgrp = lane >> 4;
    int row = 16 * w + col;
    if (f < 15) {
      int g = f / 5, kf = f % 5;
      const float* W = d ? Wih_b : Wih_f;
      src = W + (size_t)(g * 64 + row) * 160 + kf * 32 + kgrp * 8;
    } else {
      int f2 = f - 15, g = f2 >> 1, kh = f2 & 1;
      const float* W = d ? Whh_b : Whh_f;
      src = W + (size_t)(g * 64 + row) * 64 + kh * 32 + kgrp * 8;
    }
  } else {
    int s2 = slot - HEAD_W_OFF;
    int f = s2 >> 8, rw = s2 & 255;
    int w = rw >> 6, lane = rw & 63;
    int col = lane & 15, kgrp = lane >> 4;
    int gr = 16 * w + col;
    if (f < 4)      src = mw1 + (size_t)gr * 128 + f * 32 + kgrp * 8;
    else if (f < 6) src = mw2 + (size_t)gr * 64 + (f - 4) * 32 + kgrp * 8;
    else if (f < 8) src = mu_w + (size_t)gr * 64 + (f - 6) * 32 + kgrp * 8;
    else            src = lv_w + (size_t)gr * 64 + (f - 8) * 32 + kgrp * 8;
  }
  unsigned short* o = dst + (size_t)slot * 8;
#pragma unroll
  for (int i = 0; i < 8; i++) o[i] = f2bf(src[i]);
}

// ---------------- decide ----------------
__global__ __launch_bounds__(256) void k_decide(
    const float* __restrict__ obs, const float* __restrict__ act,
    const float* __restrict__ ln_g, const float* __restrict__ ln_b,
    const float* __restrict__ dw1, const float* __restrict__ db1,
    const float* __restrict__ dw2, const float* __restrict__ db2,
    const float* __restrict__ dw3, const float* __restrict__ db3,
    int* __restrict__ lens) {
  int b = blockIdx.x * 4 + (threadIdx.x >> 6);
  int l = threadIdx.x & 63;
  const float* o7 = obs + ((size_t)b * NPOS + CTR) * OBS;
  const float* o6 = o7 - OBS;
  const float* o5 = o7 - 2 * OBS;
  const float* o4 = o7 - 3 * OBS;
  float x0 = o7[l], x1 = o7[l + 64];
  float y60 = o6[l], y61 = o6[l + 64];
  float y50 = o5[l], y51 = o5[l + 64];
  float y40 = o4[l], y41 = o4[l + 64];
  float ap = (l < 32) ? act[((size_t)b * NPOS + 6) * ACTD + l] : 0.0f;

  float m = wmax(fmaxf(x0, x1));
  float e0 = __expf(x0 - m), e1 = __expf(x1 - m);
  float s = wsum(e0 + e1);
  float dot = wsum(e0 * (x0 - m) + e1 * (x1 - m));
  float ent = __logf(s) - dot / s;

  float d0 = wsum((x0 - y60) * (x0 - y60) + (x1 - y61) * (x1 - y61));
  float d1 = wsum((y60 - y50) * (y60 - y50) + (y61 - y51) * (y61 - y51));
  float d2 = wsum((y50 - y40) * (y50 - y40) + (y51 - y41) * (y51 - y41));
  float roc = (sqrtf(d0) + sqrtf(d1) + sqrtf(d2)) / 3.0f;

  float sop = wsum(x0 + x1);
  float sop2 = wsum(x0 * x0 + x1 * x1);
  float sap = wsum(ap);
  float sap2 = wsum(ap * ap);
  float dotoa = wsum(ap * x0);
  float mo = sop / 128.0f, ma = sap / 128.0f;
  float num = dotoa - 128.0f * mo * ma;
  float oc2 = fmaxf(sop2 - 128.0f * mo * mo, 0.0f);
  float ac2 = fmaxf(sap2 - 128.0f * ma * ma, 0.0f);
  float corr = num / (sqrtf(oc2) * sqrtf(ac2) + 1e-8f);

  float f0 = ent, f1 = roc, f2 = corr;
  float mean = (f0 + f1 + f2) / 3.0f;
  float v0 = f0 - mean, v1 = f1 - mean, v2 = f2 - mean;
  float var = (v0 * v0 + v1 * v1 + v2 * v2) / 3.0f;
  float sd = sqrtf(var + 1e-5f);
  float fn0 = v0 / sd * ln_g[0] + ln_b[0];
  float fn1 = v1 / sd * ln_g[1] + ln_b[1];
  float fn2 = v2 / sd * ln_g[2] + ln_b[2];

  float h1[16];
#pragma unroll
  for (int i = 0; i < 16; i++) {
    float a = db1[i] + fn0 * dw1[i * 3] + fn1 * dw1[i * 3 + 1] + fn2 * dw1[i * 3 + 2];
    h1[i] = fmaxf(a, 0.0f);
  }
  float h2[8];
#pragma unroll
  for (int i = 0; i < 8; i++) {
    float a = db2[i];
#pragma unroll
    for (int j = 0; j < 16; j++) a += h1[j] * dw2[i * 16 + j];
    h2[i] = fmaxf(a, 0.0f);
  }
  float best = -3.0e38f;
  int bi = 0;
#pragma unroll
  for (int i = 0; i < 14; i++) {
    float a = db3[i];
#pragma unroll
    for (int j = 0; j < 8; j++) a += h2[j] * dw3[i * 8 + j];
    if (a > best) { best = a; bi = i; }
  }
  int wl = bi + 2;
  if (l == 0) {
    lens[b] = (wl - 1) / 2 + 1;
    lens[NBATCH + b] = wl / 2 + 1;
  }
}

// ---------------- count: per-block LDS histograms ----------------
__global__ __launch_bounds__(256) void k_count(
    const int* __restrict__ lens, int* __restrict__ ctrl) {
  __shared__ int hist[16];
  const int tid = threadIdx.x, blk = blockIdx.x;
  if (tid < 16) hist[tid] = 0;
  __syncthreads();
#pragma unroll
  for (int j = 0; j < 2; j++) {
    int e = blk * EPB + j * 256 + tid;
    atomicAdd(&hist[lens[e] - 1], 1);
    atomicAdd(&hist[8 + lens[NBATCH + e] - 1], 1);
  }
  __syncthreads();
  if (tid < 16) ctrl[BH_OFF + blk * 16 + tid] = hist[tid];
}

// ---------------- scan: LPT-ordered regions (len desc), pads x32 --------------
__global__ void k_scan(int* __restrict__ ctrl, int* __restrict__ sidx) {
  __shared__ int tot[16];
  __shared__ int pss[17];
  __shared__ int border[16];   // region -> bin
  __shared__ int bstart[16];   // bin -> global start
  const int tid = threadIdx.x;
  const int* bh = ctrl + BH_OFF;
  int* bb = ctrl + BB_OFF;
  if (tid < 16) {
    int s = 0;
    for (int blk = 0; blk < NCB; blk++) {
      bb[blk * 16 + tid] = s;
      s += bh[blk * 16 + tid];
    }
    tot[tid] = s;
  }
  __syncthreads();
  if (tid == 0) {
    int acc = 0;
    for (int r = 0; r < 16; r++) {
      int bin = (r & 1) * 8 + 7 - (r >> 1);  // len 8 first, f/b interleaved
      border[r] = bin;
      pss[r] = acc;
      bstart[bin] = acc;
      acc += (tot[bin] + 31) & ~31;
    }
    pss[16] = acc;
    for (int r = 0; r < 17; r++) ctrl[r] = pss[r];
    for (int r = 0; r < 16; r++) ctrl[17 + r] = border[r];
  }
  __syncthreads();
  if (tid < 16) {
    for (int blk = 0; blk < NCB; blk++) bb[blk * 16 + tid] += bstart[tid];
  }
  __syncthreads();
  for (int r = 0; r < 16; r++) {
    int bin = border[r];
    int s = pss[r] + tot[bin], e2 = pss[r + 1];
    for (int i = s + tid; i < e2; i += 64) sidx[i] = -1;
  }
}

// ---------------- place ----------------
__global__ __launch_bounds__(256) void k_place(
    const int* __restrict__ lens, const int* __restrict__ ctrl,
    int* __restrict__ sidx) {
  __shared__ int hist[16];
  __shared__ int base[16];
  const int tid = threadIdx.x, blk = blockIdx.x;
  if (tid < 16) {
    hist[tid] = 0;
    base[tid] = ctrl[BB_OFF + blk * 16 + tid];
  }
  __syncthreads();
#pragma unroll
  for (int j = 0; j < 2; j++) {
    int e = blk * EPB + j * 256 + tid;
    int binf = lens[e] - 1;
    sidx[base[binf] + atomicAdd(&hist[binf], 1)] = e;
    int binb = 8 + lens[NBATCH + e] - 1;
    sidx[base[binb] + atomicAdd(&hist[binb], 1)] = e;
  }
}

// ---------------- gru: slim registers, 3 waves/SIMD target --------------------
__global__ __launch_bounds__(256, 3) void k_gru(
    const float* __restrict__ obs, const float* __restrict__ act,
    const int* __restrict__ ctrl, const int* __restrict__ sidx,
    const unsigned short* __restrict__ wbf,
    const float* __restrict__ bih_f, const float* __restrict__ bhh_f,
    const float* __restrict__ bih_b, const float* __restrict__ bhh_b,
    unsigned short* __restrict__ comb) {
  __shared__ unsigned short Xl[2][32 * 168];
  __shared__ unsigned short Hl[2][32 * 72];
  __shared__ int ei[32];

  const int tid = threadIdx.x;
  const int p = blockIdx.x * 32;
  if (p >= ctrl[16]) return;
  int r = 0;
#pragma unroll
  for (int k = 1; k < 16; k++) r += (p >= ctrl[k]) ? 1 : 0;
  const int bin = ctrl[17 + r];
  const int d = bin >> 3;
  const int len = (bin & 7) + 1;

  if (tid < 32) ei[tid] = sidx[p + tid];
  __syncthreads();

  const int w = tid >> 6, l = tid & 63;
  const int col = l & 15, kgrp = l >> 4;
  const int gr = 16 * w + col;

  const float* bih = d ? bih_b : bih_f;
  const float* bhh = d ? bhh_b : bhh_f;
  const float bias_r = bih[gr] + bhh[gr];
  const float bias_z = bih[64 + gr] + bhh[64 + gr];
  const float bias_in = bih[128 + gr];
  const float bias_hn = bhh[128 + gr];

  // register-resident: Wih (60 regs) + vr (8). vz/vn re-read per step (volatile).
  const unsigned short* fb = wbf + ((size_t)d * 5376 + tid) * 8;
  bf16x8 wr[5], wz[5], wn[5];
#pragma unroll
  for (int kf = 0; kf < 5; kf++) {
    wr[kf] = *(const bf16x8*)(fb + (size_t)kf * 2048);
    wz[kf] = *(const bf16x8*)(fb + (size_t)(5 + kf) * 2048);
    wn[kf] = *(const bf16x8*)(fb + (size_t)(10 + kf) * 2048);
  }
  bf16x8 vr[2];
  vr[0] = *(const bf16x8*)(fb + (size_t)15 * 2048);
  vr[1] = *(const bf16x8*)(fb + (size_t)16 * 2048);

  // compact staging: 1280 float4 slots (32 rows x 40), 5/thread
  const int p0 = d ? (CTR + len - 1) : (CTR - len + 1);
  int soff[5];
  unsigned qmask = 0;
#pragma unroll
  for (int it = 0; it < 5; it++) {
    int i = tid + it * 256;
    int eloc = i / 40;
    int q = i - eloc * 40;
    int eg = ei[eloc];
    if (eg < 0) eg = ei[0];
    if (q < 32) {
      soff[it] = eg * (NPOS * OBS) + p0 * OBS + q * 4;
      qmask |= 1u << it;
    } else {
      soff[it] = eg * (NPOS * ACTD) + p0 * ACTD + (q - 32) * 4;
    }
  }
  const int sA = d ? -OBS : OBS;
  const int sB = d ? -ACTD : ACTD;
  float4 sv[5];

  auto stage_issue = [&](int t1) {
    int offA = t1 * sA, offB = t1 * sB;
#pragma unroll
    for (int it = 0; it < 5; it++) {
      bool isObs = (qmask >> it) & 1u;
      const float* bp = isObs ? obs : act;
      sv[it] = *(const float4*)(bp + soff[it] + (isObs ? offA : offB));
    }
  };
  auto stage_commit = [&](int buf) {
#pragma unroll
    for (int it = 0; it < 5; it++) {
      int i = tid + it * 256;
      int eloc = i / 40;
      int q = i - eloc * 40;
      int sdo = eloc * 168 + ((q < 32) ? q * 4 : 128 + (q - 32) * 4);
      uint2 pk;
      pk.x = cvtpk(sv[it].x, sv[it].y);
      pk.y = cvtpk(sv[it].z, sv[it].w);
      *(uint2*)(&Xl[buf][sdo]) = pk;
    }
  };

  stage_issue(0);
  stage_commit(0);
  __syncthreads();

  f32x4 hreg[2];
#pragma unroll
  for (int m = 0; m < 2; m++) hreg[m] = (f32x4){0.f, 0.f, 0.f, 0.f};

  for (int t = 0; t < len; t++) {
    const int cur = t & 1, nxt = cur ^ 1;
    const bool more = (t + 1 < len);
    if (more) stage_issue(t + 1);  // HBM loads in flight under this step

    bf16x8 vz0, vz1, vn0, vn1;
    if (t > 0) {  // L2-hot 24.6 KB working set, shared by all blocks
      vz0 = vload16(fb + (size_t)17 * 2048);
      vz1 = vload16(fb + (size_t)18 * 2048);
      vn0 = vload16(fb + (size_t)19 * 2048);
      vn1 = vload16(fb + (size_t)20 * 2048);
    }

#pragma unroll
    for (int m = 0; m < 2; m++) {
      f32x4 ar = (f32x4){0.f, 0.f, 0.f, 0.f};
      f32x4 az = (f32x4){0.f, 0.f, 0.f, 0.f};
      f32x4 ain = (f32x4){0.f, 0.f, 0.f, 0.f};
      f32x4 ahn = (f32x4){0.f, 0.f, 0.f, 0.f};
#pragma unroll
      for (int kf = 0; kf < 5; kf++) {
        bf16x8 xa = *(const bf16x8*)(&Xl[cur][(col + 16 * m) * 168 + kf * 32 + kgrp * 8]);
        ar = MFMA(xa, wr[kf], ar);
        az = MFMA(xa, wz[kf], az);
        ain = MFMA(xa, wn[kf], ain);
      }
      if (t > 0) {  // h0 == 0
        bf16x8 ha0 = *(const bf16x8*)(&Hl[cur][(col + 16 * m) * 72 + kgrp * 8]);
        ar = MFMA(ha0, vr[0], ar);
        az = MFMA(ha0, vz0, az);
        ahn = MFMA(ha0, vn0, ahn);
        bf16x8 ha1 = *(const bf16x8*)(&Hl[cur][(col + 16 * m) * 72 + 32 + kgrp * 8]);
        ar = MFMA(ha1, vr[1], ar);
        az = MFMA(ha1, vz1, az);
        ahn = MFMA(ha1, vn1, ahn);
      }
      float hvv[4];
#pragma unroll
      for (int r2 = 0; r2 < 4; r2++) {
        float air = ar[r2] + bias_r;
        float aiz = az[r2] + bias_z;
        float rg = __builtin_amdgcn_rcpf(1.0f + __expf(-air));
        float zg = __builtin_amdgcn_rcpf(1.0f + __expf(-aiz));
        float nn = fmaf(rg, ahn[r2] + bias_hn, ain[r2] + bias_in);
        float th = fmaf(-2.0f, __builtin_amdgcn_rcpf(__expf(2.0f * nn) + 1.0f), 1.0f);
        float hp = hreg[m][r2];
        float hv = fmaf(zg, hp - th, th);
        hreg[m][r2] = hv;
        hvv[r2] = hv;
      }
      if (more) {
        unsigned ua = cvtpk(hvv[0], hvv[1]);
        unsigned ub = cvtpk(hvv[2], hvv[3]);
        int row0 = (16 * m + kgrp * 4) * 72 + gr;
        Hl[nxt][row0] = (unsigned short)ua;
        Hl[nxt][row0 + 72] = (unsigned short)(ua >> 16);
        Hl[nxt][row0 + 144] = (unsigned short)ub;
        Hl[nxt][row0 + 216] = (unsigned short)(ub >> 16);
      }
    }

    if (more) {
      stage_commit(nxt);
      __syncthreads();
    }
  }

#pragma unroll
  for (int m = 0; m < 2; m++) {
#pragma unroll
    for (int r2 = 0; r2 < 4; r2++) {
      int eg = ei[16 * m + kgrp * 4 + r2];
      if (eg >= 0)
        comb[(size_t)eg * 128 + 64 * d + gr] = f2bf(hreg[m][r2]);
    }
  }
}

// ---------------- head: comb -> MLP -> mu/sigma ----------------
__global__ __launch_bounds__(256) void k_head(
    const unsigned short* __restrict__ comb, const unsigned short* __restrict__ wbf,
    const float* __restrict__ mb1, const float* __restrict__ mb2,
    const float* __restrict__ mu_b, const float* __restrict__ lv_b,
    float* __restrict__ out) {
  __shared__ unsigned short Cl[64 * 136];
  __shared__ unsigned short Hl[64 * 72];
  __shared__ unsigned short Zl[64 * 72];

  const int tid = threadIdx.x;
  const int w = tid >> 6, l = tid & 63;
  const int col = l & 15, kgrp = l >> 4;
  const int gr = 16 * w + col;
  const int base = blockIdx.x * 64;

  {
    int row = tid >> 2, sq = tid & 3;
    const uint4* src = (const uint4*)(comb + (size_t)(base + row) * 128 + sq * 32);
    uint4* dst = (uint4*)(&Cl[row * 136 + sq * 32]);
#pragma unroll
    for (int j = 0; j < 4; j++) dst[j] = src[j];
  }
  __syncthreads();

  const unsigned short* hfb = wbf + ((size_t)HEAD_W_OFF + tid) * 8;
  const float b1 = mb1[gr], b2v = mb2[gr], bmu = mu_b[gr], blv = lv_b[gr];

  f32x4 t1[4];
#pragma unroll
  for (int m = 0; m < 4; m++) t1[m] = (f32x4){0.f, 0.f, 0.f, 0.f};
#pragma unroll
  for (int kf = 0; kf < 4; kf++) {
    bf16x8 bw = *(const bf16x8*)(hfb + (size_t)kf * 2048);
#pragma unroll
    for (int m = 0; m < 4; m++) {
      bf16x8 ca = *(const bf16x8*)(&Cl[(col + 16 * m) * 136 + kf * 32 + kgrp * 8]);
      t1[m] = MFMA(ca, bw, t1[m]);
    }
  }
#pragma unroll
  for (int m = 0; m < 4; m++) {
#pragma unroll
    for (int r = 0; r < 4; r++) {
      float v = fmaxf(t1[m][r] + b1, 0.0f);
      Hl[(16 * m + kgrp * 4 + r) * 72 + gr] = f2bf(v);
    }
  }
  __syncthreads();

  f32x4 ze[4];
#pragma unroll
  for (int m = 0; m < 4; m++) ze[m] = (f32x4){0.f, 0.f, 0.f, 0.f};
#pragma unroll
  for (int kh = 0; kh < 2; kh++) {
    bf16x8 bw = *(const bf16x8*)(hfb + (size_t)(4 + kh) * 2048);
#pragma unroll
    for (int m = 0; m < 4; m++) {
      bf16x8 ha = *(const bf16x8*)(&Hl[(col + 16 * m) * 72 + kh * 32 + kgrp * 8]);
      ze[m] = MFMA(ha, bw, ze[m]);
    }
  }
#pragma unroll
  for (int m = 0; m < 4; m++) {
#pragma unroll
    for (int r = 0; r < 4; r++) {
      Zl[(16 * m + kgrp * 4 + r) * 72 + gr] = f2bf(ze[m][r] + b2v);
    }
  }
  __syncthreads();

  f32x4 amu[4], alv[4];
#pragma unroll
  for (int m = 0; m < 4; m++) {
    amu[m] = (f32x4){0.f, 0.f, 0.f, 0.f};
    alv[m] = (f32x4){0.f, 0.f, 0.f, 0.f};
  }
#pragma unroll
  for (int kh = 0; kh < 2; kh++) {
    bf16x8 bwm = *(const bf16x8*)(hfb + (size_t)(6 + kh) * 2048);
    bf16x8 bwl = *(const bf16x8*)(hfb + (size_t)(8 + kh) * 2048);
#pragma unroll
    for (int m = 0; m < 4; m++) {
      bf16x8 za = *(const bf16x8*)(&Zl[(col + 16 * m) * 72 + kh * 32 + kgrp * 8]);
      amu[m] = MFMA(za, bwm, amu[m]);
      alv[m] = MFMA(za, bwl, alv[m]);
    }
  }
#pragma unroll
  for (int m = 0; m < 4; m++) {
#pragma unroll
    for (int r = 0; r < 4; r++) {
      int e = 16 * m + kgrp * 4 + r;
      float mu = amu[m][r] + bmu;
      float sg = expf(0.5f * (alv[m][r] + blv));
      size_t o = (size_t)(base + e) * HID + gr;
      out[o] = mu;
      out[(size_t)NBATCH * HID + o] = mu;
      out[2 * (size_t)NBATCH * HID + o] = sg;
    }
  }
}

extern "C" void kernel_launch(void* const* d_in, const int* in_sizes, int n_in,
                              void* d_out, int out_size, void* d_ws, size_t ws_size,
                              hipStream_t stream) {
  const float* obs = (const float*)d_in[0];
  const float* act = (const float*)d_in[1];
  const float* ln_g = (const float*)d_in[2];
  const float* ln_b = (const float*)d_in[3];
  const float* dw1 = (const float*)d_in[4];
  const float* db1 = (const float*)d_in[5];
  const float* dw2 = (const float*)d_in[6];
  const float* db2 = (const float*)d_in[7];
  const float* dw3 = (const float*)d_in[8];
  const float* db3 = (const float*)d_in[9];
  const float* Wih_f = (const float*)d_in[10];
  const float* Whh_f = (const float*)d_in[11];
  const float* bih_f = (const float*)d_in[12];
  const float* bhh_f = (const float*)d_in[13];
  const float* Wih_b = (const float*)d_in[14];
  const float* Whh_b = (const float*)d_in[15];
  const float* bih_b = (const float*)d_in[16];
  const float* bhh_b = (const float*)d_in[17];
  const float* mw1 = (const float*)d_in[18];
  const float* mb1 = (const float*)d_in[19];
  const float* mw2 = (const float*)d_in[20];
  const float* mb2 = (const float*)d_in[21];
  const float* mu_w = (const float*)d_in[22];
  const float* mu_b = (const float*)d_in[23];
  const float* lv_w = (const float*)d_in[24];
  const float* lv_b = (const float*)d_in[25];

  int* lens = (int*)d_ws;
  int* ctrl = (int*)((char*)d_ws + CTRL_BYTE);
  int* sidx = (int*)((char*)d_ws + SIDX_BYTE);
  unsigned short* wbf = (unsigned short*)((char*)d_ws + WB_BYTE);
  unsigned short* comb = (unsigned short*)((char*)d_ws + COMB_BYTE);

  k_prep<<<(TOTAL_SLOTS + 255) / 256, 256, 0, stream>>>(
      Wih_f, Whh_f, Wih_b, Whh_b, mw1, mw2, mu_w, lv_w, wbf);
  k_decide<<<NBATCH / 4, 256, 0, stream>>>(obs, act, ln_g, ln_b, dw1, db1, dw2,
                                           db2, dw3, db3, lens);
  k_count<<<NCB, 256, 0, stream>>>(lens, ctrl);
  k_scan<<<1, 64, 0, stream>>>(ctrl, sidx);
  k_place<<<NCB, 256, 0, stream>>>(lens, ctrl, sidx);
  k_gru<<<SIDX_CAP / 32, 256, 0, stream>>>(obs, act, ctrl, sidx, wbf, bih_f,
                                           bhh_f, bih_b, bhh_b, comb);
  k_head<<<NBATCH / 64, 256, 0, stream>>>(comb, wbf, mb1, mb2, mu_b, lv_b,
                                          (float*)d_out);
}

// Round 10
// 112.851 us; speedup vs baseline: 2.5775x; 2.5775x over previous
//
#include <hip/hip_runtime.h>

#define OBS 128
#define ACTD 32
#define DIMX 160
#define HID 64
#define NBATCH 32768
#define TMAXX 8
#define CTR 7
#define NPOS 15

typedef short bf16x8 __attribute__((ext_vector_type(8)));
typedef float f32x4 __attribute__((ext_vector_type(4)));

#define MFMA(a,b,c) __builtin_amdgcn_mfma_f32_16x16x32_bf16((a),(b),(c),0,0,0)

// ws layout (bytes):
//   [0)       lens: len_f[32768], len_b[32768] ints
//   [262144)  ctrl ints: [0..16] region starts (LPT order); [17..32] region->bin;
//             [40+1024+) blockHist[64][16]
//   [278528)  sidx[66048] ints (bins padded to x32, -1 sentinel)
//   [542720)  bf16 weights, fragment-major
//   [755712)  comb bf16 [elem][64*d + hunit] (8.4 MB)
#define CTRL_BYTE 262144
#define SIDX_BYTE 278528
#define SIDX_CAP  66048
#define WB_BYTE   542720
#define COMB_BYTE 755712
#define NCB 64
#define EPB 512
#define BH_OFF (40 + 1024)
#define HEAD_W_OFF 10752
#define TOTAL_SLOTS 13312

__device__ __forceinline__ unsigned short f2bf(float f) {
  unsigned u = __float_as_uint(f);
  return (unsigned short)((u + 0x7FFFu + ((u >> 16) & 1u)) >> 16);
}
__device__ __forceinline__ unsigned cvtpk(float a, float b) {
  unsigned r;
  asm("v_cvt_pk_bf16_f32 %0, %1, %2" : "=v"(r) : "v"(a), "v"(b));
  return r;
}

__device__ __forceinline__ float wsum(float v) {
#pragma unroll
  for (int s = 1; s < 64; s <<= 1) v += __shfl_xor(v, s);
  return v;
}
__device__ __forceinline__ float wmax(float v) {
#pragma unroll
  for (int s = 1; s < 64; s <<= 1) v = fmaxf(v, __shfl_xor(v, s));
  return v;
}

// ---------------- decide ----------------
__global__ __launch_bounds__(256) void k_decide(
    const float* __restrict__ obs, const float* __restrict__ act,
    const float* __restrict__ ln_g, const float* __restrict__ ln_b,
    const float* __restrict__ dw1, const float* __restrict__ db1,
    const float* __restrict__ dw2, const float* __restrict__ db2,
    const float* __restrict__ dw3, const float* __restrict__ db3,
    int* __restrict__ lens) {
  int b = blockIdx.x * 4 + (threadIdx.x >> 6);
  int l = threadIdx.x & 63;
  const float* o7 = obs + ((size_t)b * NPOS + CTR) * OBS;
  const float* o6 = o7 - OBS;
  const float* o5 = o7 - 2 * OBS;
  const float* o4 = o7 - 3 * OBS;
  float x0 = o7[l], x1 = o7[l + 64];
  float y60 = o6[l], y61 = o6[l + 64];
  float y50 = o5[l], y51 = o5[l + 64];
  float y40 = o4[l], y41 = o4[l + 64];
  float ap = (l < 32) ? act[((size_t)b * NPOS + 6) * ACTD + l] : 0.0f;

  float m = wmax(fmaxf(x0, x1));
  float e0 = __expf(x0 - m), e1 = __expf(x1 - m);
  float s = wsum(e0 + e1);
  float dot = wsum(e0 * (x0 - m) + e1 * (x1 - m));
  float ent = __logf(s) - dot / s;

  float d0 = wsum((x0 - y60) * (x0 - y60) + (x1 - y61) * (x1 - y61));
  float d1 = wsum((y60 - y50) * (y60 - y50) + (y61 - y51) * (y61 - y51));
  float d2 = wsum((y50 - y40) * (y50 - y40) + (y51 - y41) * (y51 - y41));
  float roc = (sqrtf(d0) + sqrtf(d1) + sqrtf(d2)) / 3.0f;

  float sop = wsum(x0 + x1);
  float sop2 = wsum(x0 * x0 + x1 * x1);
  float sap = wsum(ap);
  float sap2 = wsum(ap * ap);
  float dotoa = wsum(ap * x0);
  float mo = sop / 128.0f, ma = sap / 128.0f;
  float num = dotoa - 128.0f * mo * ma;
  float oc2 = fmaxf(sop2 - 128.0f * mo * mo, 0.0f);
  float ac2 = fmaxf(sap2 - 128.0f * ma * ma, 0.0f);
  float corr = num / (sqrtf(oc2) * sqrtf(ac2) + 1e-8f);

  float f0 = ent, f1 = roc, f2 = corr;
  float mean = (f0 + f1 + f2) / 3.0f;
  float v0 = f0 - mean, v1 = f1 - mean, v2 = f2 - mean;
  float var = (v0 * v0 + v1 * v1 + v2 * v2) / 3.0f;
  float sd = sqrtf(var + 1e-5f);
  float fn0 = v0 / sd * ln_g[0] + ln_b[0];
  float fn1 = v1 / sd * ln_g[1] + ln_b[1];
  float fn2 = v2 / sd * ln_g[2] + ln_b[2];

  float h1[16];
#pragma unroll
  for (int i = 0; i < 16; i++) {
    float a = db1[i] + fn0 * dw1[i * 3] + fn1 * dw1[i * 3 + 1] + fn2 * dw1[i * 3 + 2];
    h1[i] = fmaxf(a, 0.0f);
  }
  float h2[8];
#pragma unroll
  for (int i = 0; i < 8; i++) {
    float a = db2[i];
#pragma unroll
    for (int j = 0; j < 16; j++) a += h1[j] * dw2[i * 16 + j];
    h2[i] = fmaxf(a, 0.0f);
  }
  float best = -3.0e38f;
  int bi = 0;
#pragma unroll
  for (int i = 0; i < 14; i++) {
    float a = db3[i];
#pragma unroll
    for (int j = 0; j < 8; j++) a += h2[j] * dw3[i * 8 + j];
    if (a > best) { best = a; bi = i; }
  }
  int wl = bi + 2;
  if (l == 0) {
    lens[b] = (wl - 1) / 2 + 1;
    lens[NBATCH + b] = wl / 2 + 1;
  }
}

// ---------------- count + weight-prep fused (64 blocks) ----------------
__global__ __launch_bounds__(256) void k_cp(
    const int* __restrict__ lens, int* __restrict__ ctrl,
    const float* __restrict__ Wih_f, const float* __restrict__ Whh_f,
    const float* __restrict__ Wih_b, const float* __restrict__ Whh_b,
    const float* __restrict__ mw1, const float* __restrict__ mw2,
    const float* __restrict__ mu_w, const float* __restrict__ lv_w,
    unsigned short* __restrict__ dst) {
  __shared__ int hist[16];
  const int tid = threadIdx.x, blk = blockIdx.x;
  if (tid < 16) hist[tid] = 0;
  __syncthreads();
#pragma unroll
  for (int j = 0; j < 2; j++) {
    int e = blk * EPB + j * 256 + tid;
    atomicAdd(&hist[lens[e] - 1], 1);
    atomicAdd(&hist[8 + lens[NBATCH + e] - 1], 1);
  }
  // weight conversion slice (slots blk*208.. spread: 64 blocks x 208 = 13312)
  {
    int slot = blk * 208 + (tid % 208) + (tid / 208) * 13312;  // only tid<208 valid
    if (tid < 208) {
      const float* src;
      if (slot < HEAD_W_OFF) {
        int d = slot / 5376, r = slot % 5376;
        int f = r >> 8, rw = r & 255;
        int w = rw >> 6, lane = rw & 63;
        int col = lane & 15, kgrp = lane >> 4;
        int row = 16 * w + col;
        if (f < 15) {
          int g = f / 5, kf = f % 5;
          const float* W = d ? Wih_b : Wih_f;
          src = W + (size_t)(g * 64 + row) * 160 + kf * 32 + kgrp * 8;
        } else {
          int f2 = f - 15, g = f2 >> 1, kh = f2 & 1;
          const float* W = d ? Whh_b : Whh_f;
          src = W + (size_t)(g * 64 + row) * 64 + kh * 32 + kgrp * 8;
        }
      } else {
        int s2 = slot - HEAD_W_OFF;
        int f = s2 >> 8, rw = s2 & 255;
        int w = rw >> 6, lane = rw & 63;
        int col = lane & 15, kgrp = lane >> 4;
        int gr = 16 * w + col;
        if (f < 4)      src = mw1 + (size_t)gr * 128 + f * 32 + kgrp * 8;
        else if (f < 6) src = mw2 + (size_t)gr * 64 + (f - 4) * 32 + kgrp * 8;
        else if (f < 8) src = mu_w + (size_t)gr * 64 + (f - 6) * 32 + kgrp * 8;
        else            src = lv_w + (size_t)gr * 64 + (f - 8) * 32 + kgrp * 8;
      }
      unsigned short* o = dst + (size_t)slot * 8;
#pragma unroll
      for (int i = 0; i < 8; i++) o[i] = f2bf(src[i]);
    }
  }
  __syncthreads();
  if (tid < 16) ctrl[BH_OFF + blk * 16 + tid] = hist[tid];
}

// ---------------- scan+place fused: every block recomputes the scan ----------
__global__ __launch_bounds__(256) void k_scanplace(
    const int* __restrict__ lens, int* __restrict__ ctrl,
    int* __restrict__ sidx) {
  __shared__ int hist[16];
  __shared__ int base[16];
  __shared__ int tot[16];
  __shared__ int pre[16];
  __shared__ int pss[17];
  __shared__ int border[16];
  __shared__ int bstart[16];
  const int tid = threadIdx.x, blk = blockIdx.x;
  const int* bh = ctrl + BH_OFF;
  if (tid < 16) {
    int t = 0, pr = 0;
    for (int b2 = 0; b2 < NCB; b2++) {
      int h = bh[b2 * 16 + tid];
      if (b2 < blk) pr += h;
      t += h;
    }
    tot[tid] = t;
    pre[tid] = pr;
    hist[tid] = 0;
  }
  __syncthreads();
  if (tid == 0) {
    int acc = 0;
    for (int r = 0; r < 16; r++) {
      int bin = (r & 1) * 8 + 7 - (r >> 1);  // LPT: len 8 first, f/b interleaved
      border[r] = bin;
      pss[r] = acc;
      bstart[bin] = acc;
      acc += (tot[bin] + 31) & ~31;
    }
    pss[16] = acc;
    if (blk == 0) {
      for (int r = 0; r < 17; r++) ctrl[r] = pss[r];
      for (int r = 0; r < 16; r++) ctrl[17 + r] = border[r];
    }
  }
  __syncthreads();
  if (tid < 16) base[tid] = bstart[tid] + pre[tid];
  __syncthreads();
  if (blk == 0) {  // sentinel pad fill
    for (int r = 0; r < 16; r++) {
      int bin = border[r];
      int s = pss[r] + tot[bin], e2 = pss[r + 1];
      for (int i = s + tid; i < e2; i += 256) sidx[i] = -1;
    }
  }
#pragma unroll
  for (int j = 0; j < 2; j++) {
    int e = blk * EPB + j * 256 + tid;
    int binf = lens[e] - 1;
    sidx[base[binf] + atomicAdd(&hist[binf], 1)] = e;
    int binb = 8 + lens[NBATCH + e] - 1;
    sidx[base[binb] + atomicAdd(&hist[binb], 1)] = e;
  }
}

// ---------------- gru: R8 structure + bias folded into acc init ---------------
__global__ __launch_bounds__(256, 2) void k_gru(
    const float* __restrict__ obs, const float* __restrict__ act,
    const int* __restrict__ ctrl, const int* __restrict__ sidx,
    const unsigned short* __restrict__ wbf,
    const float* __restrict__ bih_f, const float* __restrict__ bhh_f,
    const float* __restrict__ bih_b, const float* __restrict__ bhh_b,
    unsigned short* __restrict__ comb) {
  __shared__ unsigned short Xl[2][32 * 168];
  __shared__ unsigned short Hl[2][32 * 72];
  __shared__ int ei[32];

  const int tid = threadIdx.x;
  const int p = blockIdx.x * 32;
  if (p >= ctrl[16]) return;
  int r = 0;
#pragma unroll
  for (int k = 1; k < 16; k++) r += (p >= ctrl[k]) ? 1 : 0;
  const int bin = ctrl[17 + r];
  const int d = bin >> 3;
  const int len = (bin & 7) + 1;

  if (tid < 32) ei[tid] = sidx[p + tid];
  __syncthreads();

  const int w = tid >> 6, l = tid & 63;
  const int col = l & 15, kgrp = l >> 4;
  const int gr = 16 * w + col;

  const float* bih = d ? bih_b : bih_f;
  const float* bhh = d ? bhh_b : bhh_f;
  const float bias_r = bih[gr] + bhh[gr];
  const float bias_z = bih[64 + gr] + bhh[64 + gr];
  const float bias_in = bih[128 + gr];
  const float bias_hn = bhh[128 + gr];

  const unsigned short* fb = wbf + ((size_t)d * 5376 + tid) * 8;
  bf16x8 wr[5], wz[5], wn[5];
#pragma unroll
  for (int kf = 0; kf < 5; kf++) {
    wr[kf] = *(const bf16x8*)(fb + (size_t)kf * 2048);
    wz[kf] = *(const bf16x8*)(fb + (size_t)(5 + kf) * 2048);
    wn[kf] = *(const bf16x8*)(fb + (size_t)(10 + kf) * 2048);
  }
  bf16x8 vr[2], vz[2], vn[2];
#pragma unroll
  for (int kh = 0; kh < 2; kh++) {
    vr[kh] = *(const bf16x8*)(fb + (size_t)(15 + kh) * 2048);
    vz[kh] = *(const bf16x8*)(fb + (size_t)(17 + kh) * 2048);
    vn[kh] = *(const bf16x8*)(fb + (size_t)(19 + kh) * 2048);
  }

  // staging: 1280 float4 slots (32 rows x 40), 5/thread; hoisted pointers
  const int p0 = d ? (CTR + len - 1) : (CTR - len + 1);
  const float* pst[5];
  int sstr[5], sdo[5];
#pragma unroll
  for (int it = 0; it < 5; it++) {
    int i = tid + it * 256;
    int eloc = i / 40;
    int q = i - eloc * 40;
    int eg = ei[eloc];
    if (eg < 0) eg = ei[0];
    if (q < 32) {
      pst[it] = obs + ((size_t)eg * NPOS + p0) * OBS + q * 4;
      sstr[it] = d ? -OBS : OBS;
    } else {
      pst[it] = act + ((size_t)eg * NPOS + p0) * ACTD + (q - 32) * 4;
      sstr[it] = d ? -ACTD : ACTD;
    }
    sdo[it] = eloc * 168 + ((q < 32) ? q * 4 : 128 + (q - 32) * 4);
  }
  float4 sv[5];

  auto stage_issue = [&](int t1) {
#pragma unroll
    for (int it = 0; it < 5; it++)
      sv[it] = *(const float4*)(pst[it] + (ptrdiff_t)t1 * sstr[it]);
  };
  auto stage_commit = [&](int buf) {
#pragma unroll
    for (int it = 0; it < 5; it++) {
      uint2 pk;
      pk.x = cvtpk(sv[it].x, sv[it].y);
      pk.y = cvtpk(sv[it].z, sv[it].w);
      *(uint2*)(&Xl[buf][sdo[it]]) = pk;
    }
  };

  stage_issue(0);
  stage_commit(0);
  __syncthreads();

  f32x4 hreg[2];
#pragma unroll
  for (int m = 0; m < 2; m++) hreg[m] = (f32x4){0.f, 0.f, 0.f, 0.f};

  for (int t = 0; t < len; t++) {
    const int cur = t & 1, nxt = cur ^ 1;
    const bool more = (t + 1 < len);
    if (more) stage_issue(t + 1);  // HBM loads in flight under this step

    // biases pre-folded into accumulator init (MFMA C-in)
    f32x4 ar[2], az[2], ain[2], ahn[2];
#pragma unroll
    for (int m = 0; m < 2; m++) {
      ar[m] = (f32x4){bias_r, bias_r, bias_r, bias_r};
      az[m] = (f32x4){bias_z, bias_z, bias_z, bias_z};
      ain[m] = (f32x4){bias_in, bias_in, bias_in, bias_in};
      ahn[m] = (f32x4){bias_hn, bias_hn, bias_hn, bias_hn};
    }
#pragma unroll
    for (int kf = 0; kf < 5; kf++) {
#pragma unroll
      for (int m = 0; m < 2; m++) {
        bf16x8 xa = *(const bf16x8*)(&Xl[cur][(col + 16 * m) * 168 + kf * 32 + kgrp * 8]);
        ar[m] = MFMA(xa, wr[kf], ar[m]);
        az[m] = MFMA(xa, wz[kf], az[m]);
        ain[m] = MFMA(xa, wn[kf], ain[m]);
      }
    }
    if (t > 0) {  // h0 == 0
#pragma unroll
      for (int kh = 0; kh < 2; kh++) {
#pragma unroll
        for (int m = 0; m < 2; m++) {
          bf16x8 ha = *(const bf16x8*)(&Hl[cur][(col + 16 * m) * 72 + kh * 32 + kgrp * 8]);
          ar[m] = MFMA(ha, vr[kh], ar[m]);
          az[m] = MFMA(ha, vz[kh], az[m]);
          ahn[m] = MFMA(ha, vn[kh], ahn[m]);
        }
      }
    }

#pragma unroll
    for (int m = 0; m < 2; m++) {
      float hvv[4];
#pragma unroll
      for (int r2 = 0; r2 < 4; r2++) {
        float rg = __builtin_amdgcn_rcpf(1.0f + __expf(-ar[m][r2]));
        float zg = __builtin_amdgcn_rcpf(1.0f + __expf(-az[m][r2]));
        float nn = fmaf(rg, ahn[m][r2], ain[m][r2]);
        float th = fmaf(-2.0f, __builtin_amdgcn_rcpf(__expf(2.0f * nn) + 1.0f), 1.0f);
        float hp = hreg[m][r2];
        float hv = fmaf(zg, hp - th, th);
        hreg[m][r2] = hv;
        hvv[r2] = hv;
      }
      if (more) {
        unsigned ua = cvtpk(hvv[0], hvv[1]);
        unsigned ub = cvtpk(hvv[2], hvv[3]);
        int row0 = (16 * m + kgrp * 4) * 72 + gr;
        Hl[nxt][row0] = (unsigned short)ua;
        Hl[nxt][row0 + 72] = (unsigned short)(ua >> 16);
        Hl[nxt][row0 + 144] = (unsigned short)ub;
        Hl[nxt][row0 + 216] = (unsigned short)(ub >> 16);
      }
    }

    if (more) {
      stage_commit(nxt);
      __syncthreads();
    }
  }

#pragma unroll
  for (int m = 0; m < 2; m++) {
#pragma unroll
    for (int r2 = 0; r2 < 4; r2++) {
      int eg = ei[16 * m + kgrp * 4 + r2];
      if (eg >= 0)
        comb[(size_t)eg * 128 + 64 * d + gr] = f2bf(hreg[m][r2]);
    }
  }
}

// ---------------- head: comb -> MLP -> mu/sigma ----------------
__global__ __launch_bounds__(256) void k_head(
    const unsigned short* __restrict__ comb, const unsigned short* __restrict__ wbf,
    const float* __restrict__ mb1, const float* __restrict__ mb2,
    const float* __restrict__ mu_b, const float* __restrict__ lv_b,
    float* __restrict__ out) {
  __shared__ unsigned short Cl[64 * 136];
  __shared__ unsigned short Hl[64 * 72];
  __shared__ unsigned short Zl[64 * 72];

  const int tid = threadIdx.x;
  const int w = tid >> 6, l = tid & 63;
  const int col = l & 15, kgrp = l >> 4;
  const int gr = 16 * w + col;
  const int base = blockIdx.x * 64;

  {
    int row = tid >> 2, sq = tid & 3;
    const uint4* src = (const uint4*)(comb + (size_t)(base + row) * 128 + sq * 32);
    uint4* dst = (uint4*)(&Cl[row * 136 + sq * 32]);
#pragma unroll
    for (int j = 0; j < 4; j++) dst[j] = src[j];
  }
  __syncthreads();

  const unsigned short* hfb = wbf + ((size_t)HEAD_W_OFF + tid) * 8;
  const float b1 = mb1[gr], b2v = mb2[gr], bmu = mu_b[gr], blv = lv_b[gr];

  f32x4 t1[4];
#pragma unroll
  for (int m = 0; m < 4; m++) t1[m] = (f32x4){0.f, 0.f, 0.f, 0.f};
#pragma unroll
  for (int kf = 0; kf < 4; kf++) {
    bf16x8 bw = *(const bf16x8*)(hfb + (size_t)kf * 2048);
#pragma unroll
    for (int m = 0; m < 4; m++) {
      bf16x8 ca = *(const bf16x8*)(&Cl[(col + 16 * m) * 136 + kf * 32 + kgrp * 8]);
      t1[m] = MFMA(ca, bw, t1[m]);
    }
  }
#pragma unroll
  for (int m = 0; m < 4; m++) {
#pragma unroll
    for (int r = 0; r < 4; r++) {
      float v = fmaxf(t1[m][r] + b1, 0.0f);
      Hl[(16 * m + kgrp * 4 + r) * 72 + gr] = f2bf(v);
    }
  }
  __syncthreads();

  f32x4 ze[4];
#pragma unroll
  for (int m = 0; m < 4; m++) ze[m] = (f32x4){0.f, 0.f, 0.f, 0.f};
#pragma unroll
  for (int kh = 0; kh < 2; kh++) {
    bf16x8 bw = *(const bf16x8*)(hfb + (size_t)(4 + kh) * 2048);
#pragma unroll
    for (int m = 0; m < 4; m++) {
      bf16x8 ha = *(const bf16x8*)(&Hl[(col + 16 * m) * 72 + kh * 32 + kgrp * 8]);
      ze[m] = MFMA(ha, bw, ze[m]);
    }
  }
#pragma unroll
  for (int m = 0; m < 4; m++) {
#pragma unroll
    for (int r = 0; r < 4; r++) {
      Zl[(16 * m + kgrp * 4 + r) * 72 + gr] = f2bf(ze[m][r] + b2v);
    }
  }
  __syncthreads();

  f32x4 amu[4], alv[4];
#pragma unroll
  for (int m = 0; m < 4; m++) {
    amu[m] = (f32x4){0.f, 0.f, 0.f, 0.f};
    alv[m] = (f32x4){0.f, 0.f, 0.f, 0.f};
  }
#pragma unroll
  for (int kh = 0; kh < 2; kh++) {
    bf16x8 bwm = *(const bf16x8*)(hfb + (size_t)(6 + kh) * 2048);
    bf16x8 bwl = *(const bf16x8*)(hfb + (size_t)(8 + kh) * 2048);
#pragma unroll
    for (int m = 0; m < 4; m++) {
      bf16x8 za = *(const bf16x8*)(&Zl[(col + 16 * m) * 72 + kh * 32 + kgrp * 8]);
      amu[m] = MFMA(za, bwm, amu[m]);
      alv[m] = MFMA(za, bwl, alv[m]);
    }
  }
#pragma unroll
  for (int m = 0; m < 4; m++) {
#pragma unroll
    for (int r = 0; r < 4; r++) {
      int e = 16 * m + kgrp * 4 + r;
      float mu = amu[m][r] + bmu;
      float sg = expf(0.5f * (alv[m][r] + blv));
      size_t o = (size_t)(base + e) * HID + gr;
      out[o] = mu;
      out[(size_t)NBATCH * HID + o] = mu;
      out[2 * (size_t)NBATCH * HID + o] = sg;
    }
  }
}

extern "C" void kernel_launch(void* const* d_in, const int* in_sizes, int n_in,
                              void* d_out, int out_size, void* d_ws, size_t ws_size,
                              hipStream_t stream) {
  const float* obs = (const float*)d_in[0];
  const float* act = (const float*)d_in[1];
  const float* ln_g = (const float*)d_in[2];
  const float* ln_b = (const float*)d_in[3];
  const float* dw1 = (const float*)d_in[4];
  const float* db1 = (const float*)d_in[5];
  const float* dw2 = (const float*)d_in[6];
  const float* db2 = (const float*)d_in[7];
  const float* dw3 = (const float*)d_in[8];
  const float* db3 = (const float*)d_in[9];
  const float* Wih_f = (const float*)d_in[10];
  const float* Whh_f = (const float*)d_in[11];
  const float* bih_f = (const float*)d_in[12];
  const float* bhh_f = (const float*)d_in[13];
  const float* Wih_b = (const float*)d_in[14];
  const float* Whh_b = (const float*)d_in[15];
  const float* bih_b = (const float*)d_in[16];
  const float* bhh_b = (const float*)d_in[17];
  const float* mw1 = (const float*)d_in[18];
  const float* mb1 = (const float*)d_in[19];
  const float* mw2 = (const float*)d_in[20];
  const float* mb2 = (const float*)d_in[21];
  const float* mu_w = (const float*)d_in[22];
  const float* mu_b = (const float*)d_in[23];
  const float* lv_w = (const float*)d_in[24];
  const float* lv_b = (const float*)d_in[25];

  int* lens = (int*)d_ws;
  int* ctrl = (int*)((char*)d_ws + CTRL_BYTE);
  int* sidx = (int*)((char*)d_ws + SIDX_BYTE);
  unsigned short* wbf = (unsigned short*)((char*)d_ws + WB_BYTE);
  unsigned short* comb = (unsigned short*)((char*)d_ws + COMB_BYTE);

  k_decide<<<NBATCH / 4, 256, 0, stream>>>(obs, act, ln_g, ln_b, dw1, db1, dw2,
                                           db2, dw3, db3, lens);
  k_cp<<<NCB, 256, 0, stream>>>(lens, ctrl, Wih_f, Whh_f, Wih_b, Whh_b, mw1,
                                mw2, mu_w, lv_w, wbf);
  k_scanplace<<<NCB, 256, 0, stream>>>(lens, ctrl, sidx);
  k_gru<<<SIDX_CAP / 32, 256, 0, stream>>>(obs, act, ctrl, sidx, wbf, bih_f,
                                           bhh_f, bih_b, bhh_b, comb);
  k_head<<<NBATCH / 64, 256, 0, stream>>>(comb, wbf, mb1, mb2, mu_b, lv_b,
                                          (float*)d_out);
}